// Round 5
// baseline (81.099 us; speedup 1.0000x reference)
//
#include <hip/hip_runtime.h>

// MLSA-style multi-stage time-varying FIR.
// y = (sum_{n=0..20} F^n x / n!) * exp(lerp(mc[...,0]))
// F: xn[t] = sum_{d=1..49} lerp_t(mc[:, :, d]) * xa[t-d]
//
// Round-4: fixes round-3's store bug. swz(g+1) != swz(g)+1 when the octet
// index (g>>3) is odd (XOR with odd mask flips bit0: (a+1)^m == (a^m)-1).
// Both store group addresses are now swizzled individually (precomputed).
// Structure otherwise identical to round 3:
//  - pair remap: tid -> (P = tid>=384, K) owns samples 16K+8P..+7 ->
//    window/store lane stride 4 groups (64B) = round-1's low-conflict regime
//    at 12 waves/CU.
//  - window LDS word addresses precomputed once (13 regs).
//  - taps for lags 1..20 cached in registers (tap LDS reads 25 -> 15/stage).

#define FO    49      // filter order (lags 1..49)
#define FP    80      // frame period
#define NST   20      // Taylor stages
#define NB    8       // batch
#define TT    160000  // samples per batch row
#define NFR   2000    // frames
#define NC    50      // coeffs per frame
#define HALO  1024    // left halo (>= 20*49=980)
#define NT    768     // threads per block (12 waves)
#define NTH   384     // NT/2
#define RPT   8       // samples per thread
#define EE    6144    // NT*RPT extended region
#define TOUT  5120    // EE - HALO outputs per tile
#define TILES 32      // TT / TOUT coverage (32*5120 = 163840 >= 160000)
#define PADW  56      // zero pad words in front of data (underrun reach: 52)
#define NFRL  78      // tap rows per block
#define TROW  100     // tap row stride in words (49 float2 + pad; 400B)
#define NTC   10      // tap float4s cached in registers (lags 1..2*NTC)

// 16B-group XOR swizzle.
__device__ __forceinline__ int swz(int g) { return g ^ ((g >> 3) & 7); }

__global__ __launch_bounds__(NT, 3) void mlsa_kernel(
    const float* __restrict__ x, const float* __restrict__ mc,
    float* __restrict__ out) {
  __shared__ __align__(16) float sb0[PADW + EE];
  __shared__ __align__(16) float sb1[PADW + EE];
  __shared__ __align__(16) float taps[NFRL * TROW];

  const int tid  = threadIdx.x;
  const int b    = blockIdx.x >> 5;   // TILES == 32
  const int tile = blockIdx.x & 31;
  const int base = tile * TOUT - HALO;  // global sample index of local 0
  const float* __restrict__ xb  = x + b * TT;
  const float* __restrict__ mcb = mc + b * NFR * NC;

  if (tid < PADW) { sb0[tid] = 0.f; sb1[tid] = 0.f; }

  // Stage x tile into sb0 (stride-1 groups, coalesced; base%4==0, TT%4==0).
  #pragma unroll
  for (int i = 0; i < EE / 4 / NT; ++i) {
    const int q  = i * NT + tid;
    const int t0 = base + q * 4;
    float4 v = make_float4(0.f, 0.f, 0.f, 0.f);
    if (t0 >= 0 && t0 < TT) v = *(const float4*)(xb + t0);
    *(float4*)(sb0 + PADW + 4 * swz(q)) = v;
  }

  // Tap table -> LDS. Row e = frame fb+e; word 2*(d-1) = {c_d, dc_d/FP}.
  const int fb = max(base, 0) / FP;
  for (int idx = tid; idx < NFRL * FO; idx += NT) {
    const int e  = idx / FO;
    const int dm = idx - e * FO;
    const int fa = min(fb + e, NFR - 1);
    const int fn = min(fb + e + 1, NFR - 1);
    const float a0 = mcb[fa * NC + dm + 1];
    const float a1 = mcb[fn * NC + dm + 1];
    *(float2*)(taps + e * TROW + 2 * dm) = make_float2(a0, (a1 - a0) * (1.0f / FP));
  }

  // Pair remap: P wave-uniform (waves 0-5: P=0, 6-11: P=1).
  const int P  = (tid >= NTH) ? 1 : 0;
  const int K  = tid - P * NTH;
  const int g0 = base + 16 * K + 8 * P;       // first own sample (global)
  const int gc = min(max(g0, 0), TT - 1);
  const int n0 = gc / FP;                      // 8 own samples in one frame
  const int fi = n0 - fb;
  const float p0f = (float)(gc - n0 * FP);

  // Precomputed LDS word indices: window groups GB..GB+12 (each swizzled
  // individually) and the two store groups (ditto -- round-3 bug was here).
  const int GB = 4 * K - 13 + 2 * P;
  int widx[13];
  #pragma unroll
  for (int i = 0; i < 13; ++i) {
    const int q = GB + i;
    widx[i] = (q < 0) ? (PADW + 4 * q) : (PADW + 4 * swz(q));
  }
  const int sidx0 = PADW + 4 * swz(4 * K + 2 * P);
  const int sidx1 = PADW + 4 * swz(4 * K + 2 * P + 1);

  // Own 8 samples; xp persists across stages (= prev stage values).
  float xp[RPT];
  #pragma unroll
  for (int k = 0; k < 2; ++k) {
    const int t0 = g0 + 4 * k;
    float4 v = make_float4(0.f, 0.f, 0.f, 0.f);
    if (t0 >= 0 && t0 < TT) v = *(const float4*)(xb + t0);
    xp[4*k] = v.x; xp[4*k+1] = v.y; xp[4*k+2] = v.z; xp[4*k+3] = v.w;
  }
  float y[RPT];
  #pragma unroll
  for (int j = 0; j < RPT; ++j) y[j] = xp[j];

  __syncthreads();

  // Register tap cache: lags 1..2*NTC.
  const float* trow = taps + fi * TROW;
  float4 tr[NTC];
  #pragma unroll
  for (int p = 0; p < NTC; ++p) tr[p] = *(const float4*)(trow + 4 * p);

  const float* rb = sb0;
  float*       wb = sb1;
  #pragma unroll 1
  for (int s = 1; s <= NST; ++s) {
    // A[m] = stage-(s-1) value at word 16K+8P-52+m, m = 0..51.
    float A[52];
    #pragma unroll
    for (int i = 0; i < 13; ++i) {
      const float4 v = *(const float4*)(rb + widx[i]);
      A[4*i] = v.x; A[4*i+1] = v.y; A[4*i+2] = v.z; A[4*i+3] = v.w;
    }
    float acc0[RPT], acc1[RPT];
    #pragma unroll
    for (int j = 0; j < RPT; ++j) { acc0[j] = 0.f; acc1[j] = 0.f; }
    // Lags 1..2*NTC from register taps.
    #pragma unroll
    for (int p = 0; p < NTC; ++p) {
      const float4 tp = tr[p];
      const int d0 = 2 * p + 1, d1 = 2 * p + 2;
      #pragma unroll
      for (int j = 0; j < RPT; ++j) {
        const int ka = 52 + j - d0;
        const float va = (ka < 52) ? A[ka] : xp[ka - 52];
        acc0[j] = fmaf(tp.x, va, acc0[j]);
        acc1[j] = fmaf(tp.y, va, acc1[j]);
        const int kb = 52 + j - d1;
        const float vb = (kb < 52) ? A[kb] : xp[kb - 52];
        acc0[j] = fmaf(tp.z, vb, acc0[j]);
        acc1[j] = fmaf(tp.w, vb, acc1[j]);
      }
    }
    // Lags 2*NTC+1..49 from LDS taps (offset-immediate reads off trow).
    #pragma unroll
    for (int p = NTC; p < 25; ++p) {
      const float4 tp = *(const float4*)(trow + 4 * p);
      const int d0 = 2 * p + 1, d1 = 2 * p + 2;
      #pragma unroll
      for (int j = 0; j < RPT; ++j) {
        const int ka = 52 + j - d0;
        const float va = (ka < 52) ? A[ka] : xp[ka - 52];
        acc0[j] = fmaf(tp.x, va, acc0[j]);
        acc1[j] = fmaf(tp.y, va, acc1[j]);
        if (d1 <= FO) {
          const int kb = 52 + j - d1;
          const float vb = (kb < 52) ? A[kb] : xp[kb - 52];
          acc0[j] = fmaf(tp.z, vb, acc0[j]);
          acc1[j] = fmaf(tp.w, vb, acc1[j]);
        }
      }
    }
    const float ia = 1.0f / (float)s;
    #pragma unroll
    for (int j = 0; j < RPT; ++j) {
      const float xn = fmaf(p0f + (float)j, acc1[j], acc0[j]) * ia;
      y[j] += xn;
      xp[j] = xn;
    }
    {
      float4 v;
      v.x = xp[0]; v.y = xp[1]; v.z = xp[2]; v.w = xp[3];
      *(float4*)(wb + sidx0) = v;
      v.x = xp[4]; v.y = xp[5]; v.z = xp[6]; v.w = xp[7];
      *(float4*)(wb + sidx1) = v;
    }
    __syncthreads();
    const float* t = rb; rb = wb; wb = (float*)t;
  }

  // Epilogue: out = y * exp(lerp(mc[...,0])). Outputs are samples >= HALO.
  if (K >= HALO / 16 && g0 < TT) {
    const int n1 = min(n0 + 1, NFR - 1);
    const float k0 = mcb[n0 * NC];
    const float k1 = mcb[n1 * NC];
    const float dk = (k1 - k0) * (1.0f / FP);
    float* ob = out + b * TT + g0;
    #pragma unroll
    for (int k = 0; k < 2; ++k) {
      float4 v;
      #pragma unroll
      for (int e = 0; e < 4; ++e) {
        const int j = 4 * k + e;
        const float Kg = __expf(fmaf(p0f + (float)j, dk, k0));
        ((float*)&v)[e] = y[j] * Kg;
      }
      *(float4*)(ob + 4 * k) = v;
    }
  }
}

extern "C" void kernel_launch(void* const* d_in, const int* in_sizes, int n_in,
                              void* d_out, int out_size, void* d_ws, size_t ws_size,
                              hipStream_t stream) {
  const float* x  = (const float*)d_in[0];
  const float* mc = (const float*)d_in[1];
  float* out      = (float*)d_out;
  mlsa_kernel<<<NB * TILES, NT, 0, stream>>>(x, mc, out);
}